// Round 9
// baseline (102.882 us; speedup 1.0000x reference)
//
#include <hip/hip_runtime.h>

#define NFREQ   257
#define NFRAMES 3751
#define NS      480000
#define HOP     128
#define WIN     512

#define NB      32
#define BN      128                 // frames per block
#define NFT     30                  // 30*128 = 3840 frames
#define NH      32                  // half-steps: 2 fpairs * 8 ks * 2 ko
#define XWPITCH 272                 // 128 samples (256B) + 16B pad
#define XW_B    35632               // 131 rows * 272
#define WNYQ_B  1024

typedef __attribute__((ext_vector_type(8))) short short8;
typedef __attribute__((ext_vector_type(4))) float f32x4;

__device__ __forceinline__ short f2bf(float f) {
    __bf16 b = (__bf16)f;
    return __builtin_bit_cast(short, b);
}
__device__ __forceinline__ float bf2f(short s) {
    unsigned int u = ((unsigned int)(unsigned short)s) << 16;
    return __builtin_bit_cast(float, u);
}
__device__ __forceinline__ void gload_lds16(const void* g, void* l) {
    __builtin_amdgcn_global_load_lds(
        (const __attribute__((address_space(1))) void*)g,
        (__attribute__((address_space(3))) void*)l, 16, 0, 0);
}

// ---- prep: abf[2][256][512] bf16 (linear cast) + nyq row (real row 256) ----
__global__ __launch_bounds__(256)
void prep_basis3(const float* __restrict__ basis,
                 short* __restrict__ abf, short* __restrict__ wnyqG) {
    int g = blockIdx.x * 256 + threadIdx.x;
    if (g < 32768) {
        int plane = g >> 14;
        int rem   = g & 16383;
        int row   = rem >> 6;
        int kg    = rem & 63;
        const float4* p = reinterpret_cast<const float4*>(
            basis + ((size_t)(plane * NFREQ + row)) * WIN + kg * 8);
        float4 a0 = p[0], a1 = p[1];
        short8 v;
        v[0]=f2bf(a0.x); v[1]=f2bf(a0.y); v[2]=f2bf(a0.z); v[3]=f2bf(a0.w);
        v[4]=f2bf(a1.x); v[5]=f2bf(a1.y); v[6]=f2bf(a1.z); v[7]=f2bf(a1.w);
        *reinterpret_cast<short8*>(abf + ((size_t)(plane * 256 + row)) * WIN + kg * 8) = v;
    } else if (g < 32832) {
        int j = g - 32768;
        const float4* p = reinterpret_cast<const float4*>(basis + (size_t)256 * WIN + j * 8);
        float4 a0 = p[0], a1 = p[1];
        short8 v;
        v[0]=f2bf(a0.x); v[1]=f2bf(a0.y); v[2]=f2bf(a0.z); v[3]=f2bf(a0.w);
        v[4]=f2bf(a1.x); v[5]=f2bf(a1.y); v[6]=f2bf(a1.z); v[7]=f2bf(a1.w);
        *reinterpret_cast<short8*>(wnyqG + j * 8) = v;
    }
}

// ---- main: barrier-free loop; X in LDS (staged once), A direct global->VGPR ----
__global__ __launch_bounds__(256, 2)
void stft_mfma_kernel(const float* __restrict__ x,
                      const short* __restrict__ abf,
                      const short* __restrict__ wnyqG,
                      float* __restrict__ out)
{
    __shared__ __align__(16) char smem[XW_B + WNYQ_B];   // 36656 B
    char* const xw   = smem;
    char* const wnyq = smem + XW_B;

    const int tid  = threadIdx.x;
    const int wave = tid >> 6;          // 0..3 : freq sub-row (32 rows each)
    const int lane = tid & 63;
    const int lgrp = lane >> 4;
    const int l15  = lane & 15;

    // bijective XCD chunk swizzle: 960 = 8 * 120
    const int logical = (blockIdx.x & 7) * 120 + (blockIdx.x >> 3);
    const int ft = logical % NFT;
    const int b  = logical / NFT;
    const int t0 = ft * BN;

    if (wave == 0)
        gload_lds16((const char*)wnyqG + lane * 16, wnyq);

    // ---- prologue: fp32 x window -> bf16 LDS, padded rows, reflect at edges ----
    {
        const float* __restrict__ xb = x + (size_t)b * NS;
        const int sbase = t0 * 128 - 256;
        #pragma unroll
        for (int i = 0; i < 9; ++i) {
            int g = tid + i * 256;                 // 8-sample (16B) group
            if (g < 2096) {
                int ix = sbase + g * 8;
                short8 v;
                if (ix >= 0 && ix + 8 <= NS) {
                    const float4* p = reinterpret_cast<const float4*>(xb + ix);
                    float4 a0 = p[0], a1 = p[1];
                    v[0]=f2bf(a0.x); v[1]=f2bf(a0.y); v[2]=f2bf(a0.z); v[3]=f2bf(a0.w);
                    v[4]=f2bf(a1.x); v[5]=f2bf(a1.y); v[6]=f2bf(a1.z); v[7]=f2bf(a1.w);
                } else {
                    #pragma unroll
                    for (int q = 0; q < 8; ++q) {
                        int idx = ix + q;
                        if (idx < 0) idx = -idx;
                        if (idx >= NS + 256) { v[q] = 0; continue; }
                        if (idx >= NS) idx = 2 * NS - 2 - idx;
                        v[q] = f2bf(xb[idx]);
                    }
                }
                *reinterpret_cast<short8*>(xw + (g >> 4) * XWPITCH + (g & 15) * 16) = v;
            }
        }
    }
    __syncthreads();    // the ONLY barrier

    // per-lane A base: row = wave*32 + l15 (+m*16), k-elem = lgrp*8
    const char* const aB = (const char*)abf + wave * 32768 + l15 * 1024 + lgrp * 16;

    f32x4 accR[2][8], accI[2][8];
    #pragma unroll
    for (int m = 0; m < 2; ++m)
        #pragma unroll
        for (int n = 0; n < 8; ++n) {
            accR[m][n] = f32x4{0.f,0.f,0.f,0.f};
            accI[m][n] = f32x4{0.f,0.f,0.f,0.f};
        }

    short8 R0[2], I0[2], R1[2], I1[2];

    // h -> byte offset: fp=h>>4 (<<17), ks=(h>>1)&7 (<<7), ko=h&1 (<<6)
    #define AOFF(h) ((((h) >> 4) << 17) + ((((h) >> 1) & 7) << 7) + (((h) & 1) << 6))

    // prologue loads: half-step 0 into set0
    #pragma unroll
    for (int m = 0; m < 2; ++m) {
        R0[m] = *reinterpret_cast<const short8*>(aB + m * 16384);
        I0[m] = *reinterpret_cast<const short8*>(aB + 262144 + m * 16384);
    }

    #define COMPUTE(h, R, I)                                                        \
    {                                                                               \
        int r8 = ((((h) >> 1) & 7) << 7) + (((h) & 1) << 6) + lgrp * 16;            \
        int T  = r8 + ((r8 >> 4) & 0x30);                                           \
        const char* xwl = xw + l15 * XWPITCH + T;                                   \
        _Pragma("unroll")                                                           \
        for (int nh = 0; nh < 2; ++nh) {                                            \
            short8 xv[4];                                                           \
            _Pragma("unroll")                                                       \
            for (int j = 0; j < 4; ++j)                                             \
                xv[j] = *reinterpret_cast<const short8*>(                           \
                    xwl + (nh * 4 + j) * (16 * XWPITCH));                           \
            _Pragma("unroll")                                                       \
            for (int m = 0; m < 2; ++m)                                             \
                _Pragma("unroll")                                                   \
                for (int j = 0; j < 4; ++j) {                                       \
                    accR[m][nh*4+j] = __builtin_amdgcn_mfma_f32_16x16x32_bf16(      \
                        (R)[m], xv[j], accR[m][nh*4+j], 0, 0, 0);                   \
                    accI[m][nh*4+j] = __builtin_amdgcn_mfma_f32_16x16x32_bf16(      \
                        (I)[m], xv[j], accI[m][nh*4+j], 0, 0, 0);                   \
                }                                                                   \
        }                                                                           \
    }

    #pragma unroll 1
    for (int hh = 0; hh < NH; hh += 2) {
        {   // prefetch h = hh+1 into set1
            const int boff = AOFF(hh + 1);
            #pragma unroll
            for (int m = 0; m < 2; ++m) {
                R1[m] = *reinterpret_cast<const short8*>(aB + boff + m * 16384);
                I1[m] = *reinterpret_cast<const short8*>(aB + boff + 262144 + m * 16384);
            }
        }
        COMPUTE(hh, R0, I0);
        if (hh + 2 < NH) {   // prefetch h = hh+2 into set0
            const int boff = AOFF(hh + 2);
            #pragma unroll
            for (int m = 0; m < 2; ++m) {
                R0[m] = *reinterpret_cast<const short8*>(aB + boff + m * 16384);
                I0[m] = *reinterpret_cast<const short8*>(aB + boff + 262144 + m * 16384);
            }
        }
        COMPUTE(hh + 1, R1, I1);

        if ((hh & 15) == 14) {           // end of fpair: s = 7 or 15 done
            const int fp = hh >> 4;
            float* ob = out + (size_t)b * NFREQ * NFRAMES;
            const int fb = fp * 128 + wave * 32 + lgrp * 4;
            const int tb = t0 + l15;
            #pragma unroll
            for (int m = 0; m < 2; ++m)
                #pragma unroll
                for (int nt = 0; nt < 8; ++nt) {
                    int t = tb + nt * 16;
                    if (t < NFRAMES) {
                        #pragma unroll
                        for (int r = 0; r < 4; ++r) {
                            int f = fb + m * 16 + r;
                            float vr = accR[m][nt][r], vi = accI[m][nt][r];
                            ob[(size_t)f * NFRAMES + t] = sqrtf(vr * vr + vi * vi);
                        }
                    }
                    accR[m][nt] = f32x4{0.f,0.f,0.f,0.f};
                    accI[m][nt] = f32x4{0.f,0.f,0.f,0.f};
                }
        }
    }

    // ---- Nyquist tail: f=256, |dot(x_frame, w)|; x & w in LDS ----
    {
        const int fl = wave * 32 + (lane & 31);       // local frame 0..127
        const int h  = lane >> 5;                     // window half
        const int xbase = (fl + 2 * h) * XWPITCH;
        const int wbase = h * 512;
        float acc = 0.f;
        #pragma unroll
        for (int j = 0; j < 32; ++j) {
            short8 xv8 = *reinterpret_cast<const short8*>(
                xw + xbase + (j >> 4) * XWPITCH + (j & 15) * 16);
            short8 wv8 = *reinterpret_cast<const short8*>(wnyq + wbase + j * 16);
            #pragma unroll
            for (int q = 0; q < 8; ++q)
                acc = fmaf(bf2f(xv8[q]), bf2f(wv8[q]), acc);
        }
        acc += __shfl_xor(acc, 32);
        int t = t0 + fl;
        if (h == 0 && t < NFRAMES)
            out[((size_t)b * NFREQ + 256) * NFRAMES + t] = fabsf(acc);
    }
}

extern "C" void kernel_launch(void* const* d_in, const int* in_sizes, int n_in,
                              void* d_out, int out_size, void* d_ws, size_t ws_size,
                              hipStream_t stream) {
    const float* x     = (const float*)d_in[0];
    const float* basis = (const float*)d_in[1];
    float* out = (float*)d_out;

    short* abf   = (short*)d_ws;                      // 2*256*512 bf16 = 512 KB
    short* wnyqG = abf + 262144;                      // 512 bf16

    prep_basis3<<<dim3(129), 256, 0, stream>>>(basis, abf, wnyqG);
    stft_mfma_kernel<<<dim3(NFT * NB), 256, 0, stream>>>(x, abf, wnyqG, out);  // 960 blocks
}